// Round 13
// baseline (393.858 us; speedup 1.0000x reference)
//
#include <hip/hip_runtime.h>
#include <hip/hip_bf16.h>

#define EPSV 1e-5f

typedef float vf2 __attribute__((ext_vector_type(2)));

// workspace float offsets (stats/params region)
#define WS_SUM0   0
#define WS_SSQ0   64
#define WS_SUM1   128
#define WS_SSQ1   192
#define WS_SUM2   256
#define WS_SSQ2   320
#define WS_AL0    384
#define WS_BE0    448
#define WS_ZBG    512
#define WS_T1BG   576      // 64*32
#define WS_AL1    2624
#define WS_BE1    2688
#define WS_T2BG   2752     // 64*16
#define WS_AL2    3776
#define WS_BE2    3840
#define WS_A2BG   3904     // 64*16
#define WS_OC     4928     // 9 used
#define WS_CU     4992     // 32: sum_{s>=4} w_rank[o][s]
#define WS_CW     5120     // 5184: pre-repacked conv table (16B aligned)
#define WS_T1     16384    // t1 buffer start; layout [m][8 chunks][256 tid][4]

#define CONV_LDS 5184

// slow repack (reads original conv_w layout) — used by prep + fallback
__device__ __forceinline__ void stage_conv(float* sW, const float* __restrict__ conv_w,
                                           int nthr) {
  for (int i = threadIdx.x; i < 8000; i += nthr) {
    int k = i / 125, rem = i - k * 125;
    int cc = rem / 25, r2 = rem - cc * 25;
    int di = r2 / 5, dj = r2 - di * 5;
    if (di < 4 && dj < 4) sW[k * 81 + cc * 16 + di * 4 + dj] = conv_w[i];
  }
  for (int k = threadIdx.x; k < 64; k += nthr) sW[k * 81 + 80] = 0.f;
}

// fast copy of the pre-repacked table (contiguous float4)
__device__ __forceinline__ void stage_conv_fast(float* sW, const float* __restrict__ cw) {
  const float4* src = (const float4*)cw;
  float4* dst = (float4*)sW;
  for (int i = threadIdx.x; i < CONV_LDS / 4; i += 256) dst[i] = src[i];
}

__device__ __forceinline__ int conv_idx(int di, int dj, int cc) {
  int idx = cc * 16 + di * 4 + dj;
  return ((di | dj) >= 0) ? idx : 80;
}

// ---------------------------------------------------------------------------
// Kernel 0: one-time repack of conv_w into ws[WS_CW] (global).
__global__ __launch_bounds__(256) void k_prep(
    const float* __restrict__ conv_w, float* __restrict__ ws) {
  float* cw = ws + WS_CW;
  const int gid = blockIdx.x * 256 + threadIdx.x;
  for (int i = gid; i < 8000; i += gridDim.x * 256) {
    int k = i / 125, rem = i - k * 125;
    int cc = rem / 25, r2 = rem - cc * 25;
    int di = r2 / 5, dj = r2 - di * 5;
    if (di < 4 && dj < 4) cw[k * 81 + cc * 16 + di * 4 + dj] = conv_w[i];
  }
  for (int k = gid; k < 64; k += gridDim.x * 256) cw[k * 81 + 80] = 0.f;
}

// ---------------------------------------------------------------------------
// Kernel 1 (fast): BN0 statistics over active 16 positions; prepped table.
__global__ __launch_bounds__(256) void k_stats0f(
    const int* __restrict__ x, const float* __restrict__ conv_b,
    float* __restrict__ ws, int M) {
  __shared__ float sW[CONV_LDS];
  stage_conv_fast(sW, ws + WS_CW);
  __syncthreads();
  const int tid = threadIdx.x;
  const int mg = tid & 3;
  const int k  = tid >> 2;
  const float cb = conv_b[k];
  const float* Wk = &sW[k * 81];
  float s = 0.f, ss = 0.f;
  for (int m = blockIdx.x * 4 + mg; m < M; m += gridDim.x * 4) {
    int r[5], c[5];
    const int2* xp = (const int2*)(x + m * 10);
#pragma unroll
    for (int cc = 0; cc < 5; ++cc) { int2 t = xp[cc]; r[cc] = t.x; c[cc] = t.y; }
#pragma unroll
    for (int y = 0; y < 4; ++y) {
#pragma unroll
      for (int xx = 0; xx < 4; ++xx) {
        float v = cb;
#pragma unroll
        for (int cc = 0; cc < 5; ++cc)
          v += Wk[conv_idx(r[cc] - y, c[cc] - xx, cc)];
        s += v;
        ss += v * v;
      }
    }
  }
  s  += __shfl_xor(s, 1);  s  += __shfl_xor(s, 2);
  ss += __shfl_xor(ss, 1); ss += __shfl_xor(ss, 2);
  if (mg == 0) {
    atomicAdd(&ws[WS_SUM0 + k], s);
    atomicAdd(&ws[WS_SSQ0 + k], ss);
  }
}

// ---------------------------------------------------------------------------
// Kernel 2: finalize BN0; background chain; seed BN1 stats; store cu[o].
__global__ __launch_bounds__(64) void k_fin0(
    const float* __restrict__ conv_b, const float* __restrict__ g0,
    const float* __restrict__ b0, const float* __restrict__ w_rank,
    const float* __restrict__ b_rank, const float* __restrict__ w_h1,
    const float* __restrict__ b_h1, float* __restrict__ ws, int M) {
  __shared__ float sS[32];
  const int t = threadIdx.x;
  if (t < 32) {
    float su = 0.f;
    for (int s2 = 0; s2 < 10; ++s2) su += w_rank[t * 10 + s2];
    sS[t] = su;
    float cu = 0.f;
    for (int s2 = 4; s2 < 10; ++s2) cu += w_rank[t * 10 + s2];
    ws[WS_CU + t] = cu;
  }
  __syncthreads();
  const int k = t;
  const float n0 = 110.f * (float)M;
  const float cb = conv_b[k];
  const float S  = ws[WS_SUM0 + k] + 94.f * (float)M * cb;
  const float SS = ws[WS_SSQ0 + k] + 94.f * (float)M * cb * cb;
  const float mu = S / n0;
  const float var = SS / n0 - mu * mu;
  const float rstd = rsqrtf(var + EPSV);
  const float al = rstd * g0[k];
  const float be = b0[k] - mu * al;
  ws[WS_AL0 + k] = al;
  ws[WS_BE0 + k] = be;
  const float zbg = fmaxf(cb * al + be, 0.f);
  ws[WS_ZBG + k] = zbg;
  float r1bg[32];
#pragma unroll
  for (int o = 0; o < 32; ++o) r1bg[o] = fmaxf(zbg * sS[o] + b_rank[o], 0.f);
  float sb = 0.f, ssb = 0.f;
  for (int o = 0; o < 32; ++o) {
    float acc = b_h1[o];
#pragma unroll
    for (int i = 0; i < 32; ++i) acc += r1bg[i] * w_h1[o * 32 + i];
    ws[WS_T1BG + k * 32 + o] = acc;
    sb += acc;
    ssb += acc * acc;
  }
  ws[WS_SUM1 + k] = 7.f * (float)M * sb;
  ws[WS_SSQ1 + k] = 7.f * (float)M * ssb;
}

// ---------------------------------------------------------------------------
// Kernel 3 (fast path): conv -> r1 -> t1, single-m, packed fp32.
// Weight feed SPLIT across pipes: even o-chunks read w_h1 from LDS
// (ds_read_b64 broadcast), odd o-chunks via wave-uniform scalar loads.
__global__ __launch_bounds__(256) void k_t1(
    const int* __restrict__ x, const float* __restrict__ conv_b,
    const float* __restrict__ w_rank, const float* __restrict__ b_rank,
    const float* __restrict__ w_h1, const float* __restrict__ b_h1,
    float* __restrict__ ws, float* __restrict__ t1, int M) {
  __shared__ float sW[CONV_LDS];
  __shared__ __align__(16) float sW1[1024];
  stage_conv_fast(sW, ws + WS_CW);
  for (int i = threadIdx.x; i < 1024; i += 256) sW1[i] = w_h1[i];
  __syncthreads();
  const int tid = threadIdx.x;
  const int y = tid & 3, k = tid >> 2;
  const float cb = conv_b[k];
  const float al = ws[WS_AL0 + k], be = ws[WS_BE0 + k], zbg = ws[WS_ZBG + k];
  const float* Wk = &sW[k * 81];
  const float* cu = ws + WS_CU;
  const vf2* wrp = (const vf2*)w_rank;
  const vf2* w1p = (const vf2*)w_h1;    // SMEM path
  const vf2* w1l = (const vf2*)sW1;     // LDS path
  float4* t1v = (float4*)t1;
  float sAcc = 0.f, ssAcc = 0.f;
  for (int m = blockIdx.x; m < M; m += gridDim.x) {
    int r[5], c[5];
    const int2* xp = (const int2*)(x + m * 10);
#pragma unroll
    for (int cc = 0; cc < 5; ++cc) { int2 t = xp[cc]; r[cc] = t.x; c[cc] = t.y; }
    float a0[4];
#pragma unroll
    for (int xx = 0; xx < 4; ++xx) {
      float v = cb;
#pragma unroll
      for (int cc = 0; cc < 5; ++cc)
        v += Wk[conv_idx(r[cc] - y, c[cc] - xx, cc)];
      a0[xx] = fmaxf(al * v + be, 0.f);
    }
    vf2 a0p[2];
    a0p[0].x = a0[0]; a0p[0].y = a0[1];
    a0p[1].x = a0[2]; a0p[1].y = a0[3];
    vf2 r1p[16];
#pragma unroll
    for (int o2 = 0; o2 < 16; ++o2) {
      const int oa = 2 * o2, ob = oa + 1;
      vf2 accA = a0p[0] * wrp[oa * 5];
      accA += a0p[1] * wrp[oa * 5 + 1];
      vf2 accB = a0p[0] * wrp[ob * 5];
      accB += a0p[1] * wrp[ob * 5 + 1];
      vf2 rr;
      rr.x = fmaxf(b_rank[oa] + zbg * cu[oa] + accA.x + accA.y, 0.f);
      rr.y = fmaxf(b_rank[ob] + zbg * cu[ob] + accB.x + accB.y, 0.f);
      r1p[o2] = rr;
    }
#pragma unroll
    for (int chv = 0; chv < 8; ++chv) {
      float acc[4];
#pragma unroll
      for (int u = 0; u < 4; ++u) {
        const int o = chv * 4 + u;
        vf2 acc2 = {0.f, 0.f};
        if ((chv & 1) == 0) {
#pragma unroll
          for (int i = 0; i < 16; ++i) acc2 += r1p[i] * w1l[o * 16 + i];
        } else {
#pragma unroll
          for (int i = 0; i < 16; ++i) acc2 += r1p[i] * w1p[o * 16 + i];
        }
        float a = b_h1[o] + acc2.x + acc2.y;
        acc[u] = a;
        sAcc += a;
        ssAcc += a * a;
      }
      float4 st; st.x = acc[0]; st.y = acc[1]; st.z = acc[2]; st.w = acc[3];
      t1v[((size_t)m * 8 + chv) * 256 + tid] = st;   // chunk-major, coalesced
    }
  }
  sAcc  += __shfl_xor(sAcc, 1);  sAcc  += __shfl_xor(sAcc, 2);
  ssAcc += __shfl_xor(ssAcc, 1); ssAcc += __shfl_xor(ssAcc, 2);
  if (y == 0) {
    atomicAdd(&ws[WS_SUM1 + k], sAcc);
    atomicAdd(&ws[WS_SSQ1 + k], ssAcc);
  }
}

// ---------------------------------------------------------------------------
// Kernel 4: finalize BN1; background a1_bg -> t2_bg; seed BN2 stats.
__global__ __launch_bounds__(64) void k_fin1(
    const float* __restrict__ g1, const float* __restrict__ b1,
    const float* __restrict__ w_h2, const float* __restrict__ b_h2,
    float* __restrict__ ws, int M) {
  const int k = threadIdx.x;
  const float n1 = (float)M * 11.f * 32.f;
  const float S = ws[WS_SUM1 + k], SS = ws[WS_SSQ1 + k];
  const float mu = S / n1;
  const float var = SS / n1 - mu * mu;
  const float rstd = rsqrtf(var + EPSV);
  const float al = rstd * g1[k];
  const float be = b1[k] - mu * al;
  ws[WS_AL1 + k] = al;
  ws[WS_BE1 + k] = be;
  float a1bg[32];
#pragma unroll
  for (int o = 0; o < 32; ++o)
    a1bg[o] = fmaxf(al * ws[WS_T1BG + k * 32 + o] + be, 0.f);
  float sb = 0.f, ssb = 0.f;
  for (int p = 0; p < 16; ++p) {
    float acc = b_h2[p];
#pragma unroll
    for (int o = 0; o < 32; ++o) acc += a1bg[o] * w_h2[p * 32 + o];
    ws[WS_T2BG + k * 16 + p] = acc;
    sb += acc;
    ssb += acc * acc;
  }
  ws[WS_SUM2 + k] = 7.f * (float)M * sb;
  ws[WS_SSQ2 + k] = 7.f * (float)M * ssb;
}

// ---------------------------------------------------------------------------
// Kernel 5 (fast path): DUAL-m t1 -> BN1+relu -> layer2 -> t2 (in place).
// Weight feed split: even p-chunks LDS, odd p-chunks scalar.
__global__ __launch_bounds__(256) void k_t2(
    const float* __restrict__ w_h2, const float* __restrict__ b_h2,
    float* __restrict__ ws, float* __restrict__ t1, int M) {
  __shared__ __align__(16) float sW2[512];
  for (int i = threadIdx.x; i < 512; i += 256) sW2[i] = w_h2[i];
  __syncthreads();
  const int tid = threadIdx.x;
  const int y = tid & 3, k = tid >> 2;
  const float al1 = ws[WS_AL1 + k], be1 = ws[WS_BE1 + k];
  const vf2* w2p = (const vf2*)w_h2;
  const vf2* w2l = (const vf2*)sW2;
  float4* t1v = (float4*)t1;
  float sAcc = 0.f, ssAcc = 0.f;
  const int NP = (M + 1) >> 1;
  for (int mp = blockIdx.x; mp < NP; mp += gridDim.x) {
    const int mA = mp * 2, mB = mA + 1;
    const bool hasB = (mB < M);
    const int mBs = hasB ? mB : mA;
    vf2 a1A[16], a1B[16];
#pragma unroll
    for (int chv = 0; chv < 8; ++chv) {
      float4 vA = t1v[((size_t)mA * 8 + chv) * 256 + tid];
      float4 vB = t1v[((size_t)mBs * 8 + chv) * 256 + tid];
      vf2 pA0, pA1, pB0, pB1;
      pA0.x = fmaxf(al1 * vA.x + be1, 0.f);
      pA0.y = fmaxf(al1 * vA.y + be1, 0.f);
      pA1.x = fmaxf(al1 * vA.z + be1, 0.f);
      pA1.y = fmaxf(al1 * vA.w + be1, 0.f);
      pB0.x = fmaxf(al1 * vB.x + be1, 0.f);
      pB0.y = fmaxf(al1 * vB.y + be1, 0.f);
      pB1.x = fmaxf(al1 * vB.z + be1, 0.f);
      pB1.y = fmaxf(al1 * vB.w + be1, 0.f);
      a1A[chv * 2] = pA0; a1A[chv * 2 + 1] = pA1;
      a1B[chv * 2] = pB0; a1B[chv * 2 + 1] = pB1;
    }
    __builtin_amdgcn_sched_barrier(0);
    float sBm = 0.f, ssBm = 0.f;
#pragma unroll
    for (int pv = 0; pv < 4; ++pv) {
      float accA[4], accB[4];
#pragma unroll
      for (int u = 0; u < 4; ++u) {
        const int p = pv * 4 + u;
        vf2 a2A = {0.f, 0.f}, a2B = {0.f, 0.f};
        if ((pv & 1) == 0) {
#pragma unroll
          for (int i = 0; i < 16; ++i) {
            vf2 w = w2l[p * 16 + i];
            a2A += a1A[i] * w;
            a2B += a1B[i] * w;
          }
        } else {
#pragma unroll
          for (int i = 0; i < 16; ++i) {
            vf2 w = w2p[p * 16 + i];
            a2A += a1A[i] * w;
            a2B += a1B[i] * w;
          }
        }
        const float bb = b_h2[p];
        float aA = bb + a2A.x + a2A.y;
        float aB = bb + a2B.x + a2B.y;
        accA[u] = aA; accB[u] = aB;
        sAcc += aA; ssAcc += aA * aA;
        sBm += aB;  ssBm += aB * aB;
      }
      float4 stA; stA.x = accA[0]; stA.y = accA[1]; stA.z = accA[2]; stA.w = accA[3];
      t1v[((size_t)mA * 8 + pv) * 256 + tid] = stA;
      if (hasB) {
        float4 stB; stB.x = accB[0]; stB.y = accB[1]; stB.z = accB[2]; stB.w = accB[3];
        t1v[((size_t)mB * 8 + pv) * 256 + tid] = stB;
      }
      __builtin_amdgcn_sched_barrier(0);
    }
    if (hasB) { sAcc += sBm; ssAcc += ssBm; }
  }
  sAcc  += __shfl_xor(sAcc, 1);  sAcc  += __shfl_xor(sAcc, 2);
  ssAcc += __shfl_xor(ssAcc, 1); ssAcc += __shfl_xor(ssAcc, 2);
  if (y == 0) {
    atomicAdd(&ws[WS_SUM2 + k], sAcc);
    atomicAdd(&ws[WS_SSQ2 + k], ssAcc);
  }
}

// ---------------------------------------------------------------------------
// Kernel 6: finalize BN2; background a2_bg; background output constant.
__global__ __launch_bounds__(64) void k_fin2(
    const float* __restrict__ g2, const float* __restrict__ b2,
    const float* __restrict__ w_out, const float* __restrict__ b_out,
    float* __restrict__ ws, int M) {
  __shared__ float red[64 * 9];
  const int k = threadIdx.x;
  const float n2 = (float)M * 11.f * 16.f;
  const float S = ws[WS_SUM2 + k], SS = ws[WS_SSQ2 + k];
  const float mu = S / n2;
  const float var = SS / n2 - mu * mu;
  const float rstd = rsqrtf(var + EPSV);
  const float al = rstd * g2[k];
  const float be = b2[k] - mu * al;
  ws[WS_AL2 + k] = al;
  ws[WS_BE2 + k] = be;
  float a2bg[16];
#pragma unroll
  for (int p = 0; p < 16; ++p) {
    a2bg[p] = fmaxf(al * ws[WS_T2BG + k * 16 + p] + be, 0.f);
    ws[WS_A2BG + k * 16 + p] = a2bg[p];
  }
  for (int j = 0; j < 9; ++j) {
    float acc = 0.f;
#pragma unroll
    for (int p = 0; p < 16; ++p) {
      float wsum = 0.f;
#pragma unroll
      for (int yy = 4; yy < 11; ++yy)
        wsum += w_out[j * 11264 + k * 176 + yy * 16 + p];
      acc += a2bg[p] * wsum;
    }
    red[k * 9 + j] = acc;
  }
  __syncthreads();
  if (k < 9) {
    float acc = b_out[k];
    for (int t = 0; t < 64; ++t) acc += red[t * 9 + k];
    ws[WS_OC + k] = acc;
  }
}

// ---------------------------------------------------------------------------
// Kernel 7 (fast path): DUAL-m t2 -> BN2+relu -> output dot + reduce.
__global__ __launch_bounds__(256) void k_out(
    const float* __restrict__ w_out, const float* __restrict__ ws,
    const float* __restrict__ t1, float* __restrict__ out, int M) {
  __shared__ float sOC[9];
  __shared__ float sRedA[4][9], sRedB[4][9];
  if (threadIdx.x < 9) sOC[threadIdx.x] = ws[WS_OC + threadIdx.x];
  __syncthreads();
  const int tid = threadIdx.x;
  const int lane = tid & 63, wv = tid >> 6;
  const int y = tid & 3, k = tid >> 2;
  const float al2 = ws[WS_AL2 + k], be2 = ws[WS_BE2 + k];
  const float4* wo = (const float4*)(w_out + k * 176 + y * 16);
  const float4* t1v = (const float4*)t1;
  const int NP = (M + 1) >> 1;
  bool first = true;
  for (int mp = blockIdx.x; mp < NP; mp += gridDim.x) {
    if (!first) __syncthreads();
    first = false;
    const int mA = mp * 2, mB = mA + 1;
    const bool hasB = (mB < M);
    const int mBs = hasB ? mB : mA;
    vf2 a2A[8], a2B[8];
#pragma unroll
    for (int iv = 0; iv < 4; ++iv) {
      float4 vA = t1v[((size_t)mA * 8 + iv) * 256 + tid];
      float4 vB = t1v[((size_t)mBs * 8 + iv) * 256 + tid];
      vf2 pA0, pA1, pB0, pB1;
      pA0.x = fmaxf(al2 * vA.x + be2, 0.f);
      pA0.y = fmaxf(al2 * vA.y + be2, 0.f);
      pA1.x = fmaxf(al2 * vA.z + be2, 0.f);
      pA1.y = fmaxf(al2 * vA.w + be2, 0.f);
      pB0.x = fmaxf(al2 * vB.x + be2, 0.f);
      pB0.y = fmaxf(al2 * vB.y + be2, 0.f);
      pB1.x = fmaxf(al2 * vB.z + be2, 0.f);
      pB1.y = fmaxf(al2 * vB.w + be2, 0.f);
      a2A[iv * 2] = pA0; a2A[iv * 2 + 1] = pA1;
      a2B[iv * 2] = pB0; a2B[iv * 2 + 1] = pB1;
    }
    float poA[9], poB[9];
#pragma unroll
    for (int j = 0; j < 9; ++j) {
      float4 w0 = wo[j * 2816 + 0], w1 = wo[j * 2816 + 1];
      float4 w2 = wo[j * 2816 + 2], w3 = wo[j * 2816 + 3];
      vf2 aA = {0.f, 0.f}, aB = {0.f, 0.f};
      vf2 t;
      t.x = w0.x; t.y = w0.y; aA += a2A[0] * t; aB += a2B[0] * t;
      t.x = w0.z; t.y = w0.w; aA += a2A[1] * t; aB += a2B[1] * t;
      t.x = w1.x; t.y = w1.y; aA += a2A[2] * t; aB += a2B[2] * t;
      t.x = w1.z; t.y = w1.w; aA += a2A[3] * t; aB += a2B[3] * t;
      t.x = w2.x; t.y = w2.y; aA += a2A[4] * t; aB += a2B[4] * t;
      t.x = w2.z; t.y = w2.w; aA += a2A[5] * t; aB += a2B[5] * t;
      t.x = w3.x; t.y = w3.y; aA += a2A[6] * t; aB += a2B[6] * t;
      t.x = w3.z; t.y = w3.w; aA += a2A[7] * t; aB += a2B[7] * t;
      poA[j] = aA.x + aA.y;
      poB[j] = aB.x + aB.y;
    }
#pragma unroll
    for (int j = 0; j < 9; ++j) {
      float vA = poA[j], vB = poB[j];
      vA += __shfl_xor(vA, 1);  vB += __shfl_xor(vB, 1);
      vA += __shfl_xor(vA, 2);  vB += __shfl_xor(vB, 2);
      vA += __shfl_xor(vA, 4);  vB += __shfl_xor(vB, 4);
      vA += __shfl_xor(vA, 8);  vB += __shfl_xor(vB, 8);
      vA += __shfl_xor(vA, 16); vB += __shfl_xor(vB, 16);
      vA += __shfl_xor(vA, 32); vB += __shfl_xor(vB, 32);
      poA[j] = vA; poB[j] = vB;
    }
    if (lane == 0) {
#pragma unroll
      for (int j = 0; j < 9; ++j) { sRedA[wv][j] = poA[j]; sRedB[wv][j] = poB[j]; }
    }
    __syncthreads();
    if (tid < 9) {
      float acc = sOC[tid];
#pragma unroll
      for (int w2i = 0; w2i < 4; ++w2i) acc += sRedA[w2i][tid];
      out[mA * 9 + tid] = acc;
    } else if (tid >= 64 && tid < 73 && hasB) {
      const int j = tid - 64;
      float acc = sOC[j];
#pragma unroll
      for (int w2i = 0; w2i < 4; ++w2i) acc += sRedB[w2i][j];
      out[mB * 9 + j] = acc;
    }
  }
}

// ===========================================================================
// FALLBACK PATH (ws too small): self-contained recompute kernels.
// ===========================================================================
__global__ __launch_bounds__(256) void k_stats0(
    const int* __restrict__ x, const float* __restrict__ conv_w,
    const float* __restrict__ conv_b, float* __restrict__ ws, int M) {
  __shared__ float sW[CONV_LDS];
  stage_conv(sW, conv_w, 256);
  __syncthreads();
  const int tid = threadIdx.x;
  const int mg = tid & 3;
  const int k  = tid >> 2;
  const float cb = conv_b[k];
  const float* Wk = &sW[k * 81];
  float s = 0.f, ss = 0.f;
  for (int m = blockIdx.x * 4 + mg; m < M; m += gridDim.x * 4) {
    int r[5], c[5];
    const int2* xp = (const int2*)(x + m * 10);
#pragma unroll
    for (int cc = 0; cc < 5; ++cc) { int2 t = xp[cc]; r[cc] = t.x; c[cc] = t.y; }
#pragma unroll
    for (int y = 0; y < 4; ++y) {
#pragma unroll
      for (int xx = 0; xx < 4; ++xx) {
        float v = cb;
#pragma unroll
        for (int cc = 0; cc < 5; ++cc)
          v += Wk[conv_idx(r[cc] - y, c[cc] - xx, cc)];
        s += v;
        ss += v * v;
      }
      __builtin_amdgcn_sched_barrier(0);
    }
  }
  s  += __shfl_xor(s, 1);  s  += __shfl_xor(s, 2);
  ss += __shfl_xor(ss, 1); ss += __shfl_xor(ss, 2);
  if (mg == 0) {
    atomicAdd(&ws[WS_SUM0 + k], s);
    atomicAdd(&ws[WS_SSQ0 + k], ss);
  }
}

__global__ __launch_bounds__(256) void k_stats1(
    const int* __restrict__ x, const float* __restrict__ conv_w,
    const float* __restrict__ conv_b, const float* __restrict__ w_rank,
    const float* __restrict__ b_rank, const float* __restrict__ w_h1,
    const float* __restrict__ b_h1, float* __restrict__ ws, int M) {
  __shared__ float sW[CONV_LDS];
  stage_conv(sW, conv_w, 256);
  __syncthreads();
  const int tid = threadIdx.x;
  const int y = tid & 3, k = tid >> 2;
  const float cb = conv_b[k];
  const float al = ws[WS_AL0 + k], be = ws[WS_BE0 + k], zbg = ws[WS_ZBG + k];
  const float* Wk = &sW[k * 81];
  const float* cu = ws + WS_CU;
  float sAcc = 0.f, ssAcc = 0.f;
  for (int m = blockIdx.x; m < M; m += gridDim.x) {
    int r[5], c[5];
    const int2* xp = (const int2*)(x + m * 10);
#pragma unroll
    for (int cc = 0; cc < 5; ++cc) { int2 t = xp[cc]; r[cc] = t.x; c[cc] = t.y; }
    float a0[4];
#pragma unroll
    for (int xx = 0; xx < 4; ++xx) {
      float v = cb;
#pragma unroll
      for (int cc = 0; cc < 5; ++cc)
        v += Wk[conv_idx(r[cc] - y, c[cc] - xx, cc)];
      a0[xx] = fmaxf(al * v + be, 0.f);
    }
    __builtin_amdgcn_sched_barrier(0);
    float r1[32];
#pragma unroll
    for (int o = 0; o < 32; ++o) {
      float acc = b_rank[o] + zbg * cu[o];
#pragma unroll
      for (int xx = 0; xx < 4; ++xx) acc += a0[xx] * w_rank[o * 10 + xx];
      r1[o] = fmaxf(acc, 0.f);
    }
    __builtin_amdgcn_sched_barrier(0);
    float s1 = 0.f, ss1 = 0.f;
#pragma unroll
    for (int ch = 0; ch < 4; ++ch) {
#pragma unroll
      for (int u = 0; u < 8; ++u) {
        const int o = ch * 8 + u;
        float acc = b_h1[o];
#pragma unroll
        for (int i = 0; i < 32; ++i) acc += r1[i] * w_h1[o * 32 + i];
        s1 += acc;
        ss1 += acc * acc;
      }
      __builtin_amdgcn_sched_barrier(0);
    }
    sAcc += s1;
    ssAcc += ss1;
  }
  sAcc  += __shfl_xor(sAcc, 1);  sAcc  += __shfl_xor(sAcc, 2);
  ssAcc += __shfl_xor(ssAcc, 1); ssAcc += __shfl_xor(ssAcc, 2);
  if (y == 0) {
    atomicAdd(&ws[WS_SUM1 + k], sAcc);
    atomicAdd(&ws[WS_SSQ1 + k], ssAcc);
  }
}

__global__ __launch_bounds__(256) void k_stats2(
    const int* __restrict__ x, const float* __restrict__ conv_w,
    const float* __restrict__ conv_b, const float* __restrict__ w_rank,
    const float* __restrict__ b_rank, const float* __restrict__ w_h1,
    const float* __restrict__ b_h1, const float* __restrict__ w_h2,
    const float* __restrict__ b_h2, float* __restrict__ ws, int M) {
  __shared__ float sW[CONV_LDS];
  stage_conv(sW, conv_w, 256);
  __syncthreads();
  const int tid = threadIdx.x;
  const int y = tid & 3, k = tid >> 2;
  const float cb = conv_b[k];
  const float al = ws[WS_AL0 + k], be = ws[WS_BE0 + k], zbg = ws[WS_ZBG + k];
  const float al1 = ws[WS_AL1 + k], be1 = ws[WS_BE1 + k];
  const float* Wk = &sW[k * 81];
  const float* cu = ws + WS_CU;
  float sAcc = 0.f, ssAcc = 0.f;
  for (int m = blockIdx.x; m < M; m += gridDim.x) {
    int r[5], c[5];
    const int2* xp = (const int2*)(x + m * 10);
#pragma unroll
    for (int cc = 0; cc < 5; ++cc) { int2 t = xp[cc]; r[cc] = t.x; c[cc] = t.y; }
    float a0[4];
#pragma unroll
    for (int xx = 0; xx < 4; ++xx) {
      float v = cb;
#pragma unroll
      for (int cc = 0; cc < 5; ++cc)
        v += Wk[conv_idx(r[cc] - y, c[cc] - xx, cc)];
      a0[xx] = fmaxf(al * v + be, 0.f);
    }
    __builtin_amdgcn_sched_barrier(0);
    float r1[32];
#pragma unroll
    for (int o = 0; o < 32; ++o) {
      float acc = b_rank[o] + zbg * cu[o];
#pragma unroll
      for (int xx = 0; xx < 4; ++xx) acc += a0[xx] * w_rank[o * 10 + xx];
      r1[o] = fmaxf(acc, 0.f);
    }
    __builtin_amdgcn_sched_barrier(0);
    float t2[16];
#pragma unroll
    for (int p = 0; p < 16; ++p) t2[p] = b_h2[p];
#pragma unroll
    for (int ch = 0; ch < 4; ++ch) {
      float a1c[8];
#pragma unroll
      for (int u = 0; u < 8; ++u) {
        const int o = ch * 8 + u;
        float acc = b_h1[o];
#pragma unroll
        for (int i = 0; i < 32; ++i) acc += r1[i] * w_h1[o * 32 + i];
        a1c[u] = fmaxf(al1 * acc + be1, 0.f);
      }
      __builtin_amdgcn_sched_barrier(0);
#pragma unroll
      for (int p = 0; p < 16; ++p) {
        float acc = t2[p];
#pragma unroll
        for (int u = 0; u < 8; ++u) acc += a1c[u] * w_h2[p * 32 + ch * 8 + u];
        t2[p] = acc;
      }
      __builtin_amdgcn_sched_barrier(0);
    }
    float s2l = 0.f, ss2l = 0.f;
#pragma unroll
    for (int p = 0; p < 16; ++p) { s2l += t2[p]; ss2l += t2[p] * t2[p]; }
    sAcc += s2l;
    ssAcc += ss2l;
  }
  sAcc  += __shfl_xor(sAcc, 1);  sAcc  += __shfl_xor(sAcc, 2);
  ssAcc += __shfl_xor(ssAcc, 1); ssAcc += __shfl_xor(ssAcc, 2);
  if (y == 0) {
    atomicAdd(&ws[WS_SUM2 + k], sAcc);
    atomicAdd(&ws[WS_SSQ2 + k], ssAcc);
  }
}

__global__ __launch_bounds__(256) void k_final(
    const int* __restrict__ x, const float* __restrict__ conv_w,
    const float* __restrict__ conv_b, const float* __restrict__ w_rank,
    const float* __restrict__ b_rank, const float* __restrict__ w_h1,
    const float* __restrict__ b_h1, const float* __restrict__ w_h2,
    const float* __restrict__ b_h2, const float* __restrict__ w_out,
    const float* __restrict__ ws, float* __restrict__ out, int M) {
  __shared__ float sW[CONV_LDS];
  __shared__ float sOC[9];
  __shared__ float sRed[4][9];
  stage_conv(sW, conv_w, 256);
  if (threadIdx.x < 9) sOC[threadIdx.x] = ws[WS_OC + threadIdx.x];
  __syncthreads();
  const int tid = threadIdx.x;
  const int lane = tid & 63, wv = tid >> 6;
  const int y = tid & 3, k = tid >> 2;
  const float cb = conv_b[k];
  const float al = ws[WS_AL0 + k], be = ws[WS_BE0 + k], zbg = ws[WS_ZBG + k];
  const float al1 = ws[WS_AL1 + k], be1 = ws[WS_BE1 + k];
  const float al2 = ws[WS_AL2 + k], be2 = ws[WS_BE2 + k];
  const float* Wk = &sW[k * 81];
  const float* cu = ws + WS_CU;
  const float4* wo = (const float4*)(w_out + k * 176 + y * 16);
  bool first = true;
  for (int m = blockIdx.x; m < M; m += gridDim.x) {
    if (!first) __syncthreads();
    first = false;
    int r[5], c[5];
    const int2* xp = (const int2*)(x + m * 10);
#pragma unroll
    for (int cc = 0; cc < 5; ++cc) { int2 t = xp[cc]; r[cc] = t.x; c[cc] = t.y; }
    float a0[4];
#pragma unroll
    for (int xx = 0; xx < 4; ++xx) {
      float v = cb;
#pragma unroll
      for (int cc = 0; cc < 5; ++cc)
        v += Wk[conv_idx(r[cc] - y, c[cc] - xx, cc)];
      a0[xx] = fmaxf(al * v + be, 0.f);
    }
    __builtin_amdgcn_sched_barrier(0);
    float r1[32];
#pragma unroll
    for (int o = 0; o < 32; ++o) {
      float acc = b_rank[o] + zbg * cu[o];
#pragma unroll
      for (int xx = 0; xx < 4; ++xx) acc += a0[xx] * w_rank[o * 10 + xx];
      r1[o] = fmaxf(acc, 0.f);
    }
    __builtin_amdgcn_sched_barrier(0);
    float t2[16];
#pragma unroll
    for (int p = 0; p < 16; ++p) t2[p] = b_h2[p];
#pragma unroll
    for (int ch = 0; ch < 4; ++ch) {
      float a1c[8];
#pragma unroll
      for (int u = 0; u < 8; ++u) {
        const int o = ch * 8 + u;
        float acc = b_h1[o];
#pragma unroll
        for (int i = 0; i < 32; ++i) acc += r1[i] * w_h1[o * 32 + i];
        a1c[u] = fmaxf(al1 * acc + be1, 0.f);
      }
      __builtin_amdgcn_sched_barrier(0);
#pragma unroll
      for (int p = 0; p < 16; ++p) {
        float acc = t2[p];
#pragma unroll
        for (int u = 0; u < 8; ++u) acc += a1c[u] * w_h2[p * 32 + ch * 8 + u];
        t2[p] = acc;
      }
      __builtin_amdgcn_sched_barrier(0);
    }
    float a2[16];
#pragma unroll
    for (int p = 0; p < 16; ++p) a2[p] = fmaxf(al2 * t2[p] + be2, 0.f);
    float po[9];
#pragma unroll
    for (int j = 0; j < 9; ++j) {
      float4 w0 = wo[j * 2816 + 0], w1 = wo[j * 2816 + 1];
      float4 w2 = wo[j * 2816 + 2], w3 = wo[j * 2816 + 3];
      po[j] = a2[0] * w0.x + a2[1] * w0.y + a2[2] * w0.z + a2[3] * w0.w
            + a2[4] * w1.x + a2[5] * w1.y + a2[6] * w1.z + a2[7] * w1.w
            + a2[8] * w2.x + a2[9] * w2.y + a2[10] * w2.z + a2[11] * w2.w
            + a2[12] * w3.x + a2[13] * w3.y + a2[14] * w3.z + a2[15] * w3.w;
    }
#pragma unroll
    for (int j = 0; j < 9; ++j) {
      float v = po[j];
      v += __shfl_xor(v, 1);
      v += __shfl_xor(v, 2);
      v += __shfl_xor(v, 4);
      v += __shfl_xor(v, 8);
      v += __shfl_xor(v, 16);
      v += __shfl_xor(v, 32);
      po[j] = v;
    }
    if (lane == 0) {
#pragma unroll
      for (int j = 0; j < 9; ++j) sRed[wv][j] = po[j];
    }
    __syncthreads();
    if (tid < 9) {
      float acc = sOC[tid];
#pragma unroll
      for (int w2i = 0; w2i < 4; ++w2i) acc += sRed[w2i][tid];
      out[m * 9 + tid] = acc;
    }
  }
}

// ---------------------------------------------------------------------------
extern "C" void kernel_launch(void* const* d_in, const int* in_sizes, int n_in,
                              void* d_out, int out_size, void* d_ws, size_t ws_size,
                              hipStream_t stream) {
  const int*   x      = (const int*)d_in[0];
  const float* conv_w = (const float*)d_in[1];
  const float* conv_b = (const float*)d_in[2];
  const float* bn0_g  = (const float*)d_in[3];
  const float* bn0_b  = (const float*)d_in[4];
  const float* w_rank = (const float*)d_in[5];
  const float* b_rank = (const float*)d_in[6];
  const float* w_h1   = (const float*)d_in[7];
  const float* b_h1   = (const float*)d_in[8];
  const float* bn1_g  = (const float*)d_in[9];
  const float* bn1_b  = (const float*)d_in[10];
  const float* w_h2   = (const float*)d_in[11];
  const float* b_h2   = (const float*)d_in[12];
  const float* bn2_g  = (const float*)d_in[13];
  const float* bn2_b  = (const float*)d_in[14];
  const float* w_out  = (const float*)d_in[15];
  const float* b_out  = (const float*)d_in[16];
  float* out = (float*)d_out;
  float* ws  = (float*)d_ws;
  const int M = in_sizes[0] / 10;
  const size_t need = ((size_t)WS_T1 + (size_t)M * 8192) * sizeof(float);
  const int NP = (M + 1) >> 1;
  const int gridp = NP < 2048 ? NP : 2048;

  hipMemsetAsync(ws, 0, 384 * sizeof(float), stream);

  if (ws_size >= need) {
    float* t1 = ws + WS_T1;
    k_prep<<<8, 256, 0, stream>>>(conv_w, ws);
    k_stats0f<<<1024, 256, 0, stream>>>(x, conv_b, ws, M);
    k_fin0<<<1, 64, 0, stream>>>(conv_b, bn0_g, bn0_b, w_rank, b_rank, w_h1, b_h1, ws, M);
    k_t1<<<2048, 256, 0, stream>>>(x, conv_b, w_rank, b_rank, w_h1, b_h1, ws, t1, M);
    k_fin1<<<1, 64, 0, stream>>>(bn1_g, bn1_b, w_h2, b_h2, ws, M);
    k_t2<<<gridp, 256, 0, stream>>>(w_h2, b_h2, ws, t1, M);
    k_fin2<<<1, 64, 0, stream>>>(bn2_g, bn2_b, w_out, b_out, ws, M);
    k_out<<<gridp, 256, 0, stream>>>(w_out, ws, t1, out, M);
  } else {
    k_stats0<<<512, 256, 0, stream>>>(x, conv_w, conv_b, ws, M);
    k_fin0<<<1, 64, 0, stream>>>(conv_b, bn0_g, bn0_b, w_rank, b_rank, w_h1, b_h1, ws, M);
    k_stats1<<<1024, 256, 0, stream>>>(x, conv_w, conv_b, w_rank, b_rank, w_h1, b_h1,
                                       ws, M);
    k_fin1<<<1, 64, 0, stream>>>(bn1_g, bn1_b, w_h2, b_h2, ws, M);
    k_stats2<<<1024, 256, 0, stream>>>(x, conv_w, conv_b, w_rank, b_rank, w_h1, b_h1,
                                       w_h2, b_h2, ws, M);
    k_fin2<<<1, 64, 0, stream>>>(bn2_g, bn2_b, w_out, b_out, ws, M);
    k_final<<<1024, 256, 0, stream>>>(x, conv_w, conv_b, w_rank, b_rank, w_h1, b_h1,
                                      w_h2, b_h2, w_out, ws, out, M);
  }
}

// Round 14
// 345.593 us; speedup vs baseline: 1.1397x; 1.1397x over previous
//
#include <hip/hip_runtime.h>
#include <hip/hip_bf16.h>

#define EPSV 1e-5f

typedef float vf2 __attribute__((ext_vector_type(2)));

// workspace float offsets (stats/params region)
#define WS_SUM0   0
#define WS_SSQ0   64
#define WS_SUM1   128
#define WS_SSQ1   192
#define WS_SUM2   256
#define WS_SSQ2   320
#define WS_AL0    384
#define WS_BE0    448
#define WS_ZBG    512
#define WS_T1BG   576      // 64*32
#define WS_AL1    2624
#define WS_BE1    2688
#define WS_T2BG   2752     // 64*16
#define WS_AL2    3776
#define WS_BE2    3840
#define WS_A2BG   3904     // 64*16
#define WS_OC     4928     // 9 used
#define WS_CU     4992     // 32: sum_{s>=4} w_rank[o][s]
#define WS_CW     5120     // 5184: pre-repacked conv table (16B aligned)
#define WS_T1     16384    // t1 buffer start; layout [m][8 chunks][256 tid][4]

#define CONV_LDS 5184

// slow repack (reads original conv_w layout) — used by prep + fallback
__device__ __forceinline__ void stage_conv(float* sW, const float* __restrict__ conv_w,
                                           int nthr) {
  for (int i = threadIdx.x; i < 8000; i += nthr) {
    int k = i / 125, rem = i - k * 125;
    int cc = rem / 25, r2 = rem - cc * 25;
    int di = r2 / 5, dj = r2 - di * 5;
    if (di < 4 && dj < 4) sW[k * 81 + cc * 16 + di * 4 + dj] = conv_w[i];
  }
  for (int k = threadIdx.x; k < 64; k += nthr) sW[k * 81 + 80] = 0.f;
}

// fast copy of the pre-repacked table (contiguous float4)
__device__ __forceinline__ void stage_conv_fast(float* sW, const float* __restrict__ cw) {
  const float4* src = (const float4*)cw;
  float4* dst = (float4*)sW;
  for (int i = threadIdx.x; i < CONV_LDS / 4; i += 256) dst[i] = src[i];
}

__device__ __forceinline__ int conv_idx(int di, int dj, int cc) {
  int idx = cc * 16 + di * 4 + dj;
  return ((di | dj) >= 0) ? idx : 80;
}

// ---------------------------------------------------------------------------
// Kernel 0: one-time repack of conv_w into ws[WS_CW] (global).
__global__ __launch_bounds__(256) void k_prep(
    const float* __restrict__ conv_w, float* __restrict__ ws) {
  float* cw = ws + WS_CW;
  const int gid = blockIdx.x * 256 + threadIdx.x;
  for (int i = gid; i < 8000; i += gridDim.x * 256) {
    int k = i / 125, rem = i - k * 125;
    int cc = rem / 25, r2 = rem - cc * 25;
    int di = r2 / 5, dj = r2 - di * 5;
    if (di < 4 && dj < 4) cw[k * 81 + cc * 16 + di * 4 + dj] = conv_w[i];
  }
  for (int k = gid; k < 64; k += gridDim.x * 256) cw[k * 81 + 80] = 0.f;
}

// ---------------------------------------------------------------------------
// Kernel 1 (fast): BN0 statistics over active 16 positions; prepped table.
__global__ __launch_bounds__(256) void k_stats0f(
    const int* __restrict__ x, const float* __restrict__ conv_b,
    float* __restrict__ ws, int M) {
  __shared__ float sW[CONV_LDS];
  stage_conv_fast(sW, ws + WS_CW);
  __syncthreads();
  const int tid = threadIdx.x;
  const int mg = tid & 3;
  const int k  = tid >> 2;
  const float cb = conv_b[k];
  const float* Wk = &sW[k * 81];
  float s = 0.f, ss = 0.f;
  for (int m = blockIdx.x * 4 + mg; m < M; m += gridDim.x * 4) {
    int r[5], c[5];
    const int2* xp = (const int2*)(x + m * 10);
#pragma unroll
    for (int cc = 0; cc < 5; ++cc) { int2 t = xp[cc]; r[cc] = t.x; c[cc] = t.y; }
#pragma unroll
    for (int y = 0; y < 4; ++y) {
#pragma unroll
      for (int xx = 0; xx < 4; ++xx) {
        float v = cb;
#pragma unroll
        for (int cc = 0; cc < 5; ++cc)
          v += Wk[conv_idx(r[cc] - y, c[cc] - xx, cc)];
        s += v;
        ss += v * v;
      }
      __builtin_amdgcn_sched_barrier(0);
    }
  }
  s  += __shfl_xor(s, 1);  s  += __shfl_xor(s, 2);
  ss += __shfl_xor(ss, 1); ss += __shfl_xor(ss, 2);
  if (mg == 0) {
    atomicAdd(&ws[WS_SUM0 + k], s);
    atomicAdd(&ws[WS_SSQ0 + k], ss);
  }
}

// ---------------------------------------------------------------------------
// Kernel 2: finalize BN0; background chain; seed BN1 stats; store cu[o].
__global__ __launch_bounds__(64) void k_fin0(
    const float* __restrict__ conv_b, const float* __restrict__ g0,
    const float* __restrict__ b0, const float* __restrict__ w_rank,
    const float* __restrict__ b_rank, const float* __restrict__ w_h1,
    const float* __restrict__ b_h1, float* __restrict__ ws, int M) {
  __shared__ float sS[32];
  const int t = threadIdx.x;
  if (t < 32) {
    float su = 0.f;
    for (int s2 = 0; s2 < 10; ++s2) su += w_rank[t * 10 + s2];
    sS[t] = su;
    float cu = 0.f;
    for (int s2 = 4; s2 < 10; ++s2) cu += w_rank[t * 10 + s2];
    ws[WS_CU + t] = cu;
  }
  __syncthreads();
  const int k = t;
  const float n0 = 110.f * (float)M;
  const float cb = conv_b[k];
  const float S  = ws[WS_SUM0 + k] + 94.f * (float)M * cb;
  const float SS = ws[WS_SSQ0 + k] + 94.f * (float)M * cb * cb;
  const float mu = S / n0;
  const float var = SS / n0 - mu * mu;
  const float rstd = rsqrtf(var + EPSV);
  const float al = rstd * g0[k];
  const float be = b0[k] - mu * al;
  ws[WS_AL0 + k] = al;
  ws[WS_BE0 + k] = be;
  const float zbg = fmaxf(cb * al + be, 0.f);
  ws[WS_ZBG + k] = zbg;
  float r1bg[32];
#pragma unroll
  for (int o = 0; o < 32; ++o) r1bg[o] = fmaxf(zbg * sS[o] + b_rank[o], 0.f);
  float sb = 0.f, ssb = 0.f;
  for (int o = 0; o < 32; ++o) {
    float acc = b_h1[o];
#pragma unroll
    for (int i = 0; i < 32; ++i) acc += r1bg[i] * w_h1[o * 32 + i];
    ws[WS_T1BG + k * 32 + o] = acc;
    sb += acc;
    ssb += acc * acc;
  }
  ws[WS_SUM1 + k] = 7.f * (float)M * sb;
  ws[WS_SSQ1 + k] = 7.f * (float)M * ssb;
}

// ---------------------------------------------------------------------------
// Kernel 3 (fast path): DUAL-m conv -> r1 -> t1; weights shared between m's.
__global__ __launch_bounds__(256) void k_t1(
    const int* __restrict__ x, const float* __restrict__ conv_b,
    const float* __restrict__ w_rank, const float* __restrict__ b_rank,
    const float* __restrict__ w_h1, const float* __restrict__ b_h1,
    float* __restrict__ ws, float* __restrict__ t1, int M) {
  __shared__ float sW[CONV_LDS];
  stage_conv_fast(sW, ws + WS_CW);
  __syncthreads();
  const int tid = threadIdx.x;
  const int y = tid & 3, k = tid >> 2;
  const float cb = conv_b[k];
  const float al = ws[WS_AL0 + k], be = ws[WS_BE0 + k], zbg = ws[WS_ZBG + k];
  const float* Wk = &sW[k * 81];
  const float* cu = ws + WS_CU;
  const vf2* wrp = (const vf2*)w_rank;
  const vf2* w1p = (const vf2*)w_h1;
  float4* t1v = (float4*)t1;
  float sAcc = 0.f, ssAcc = 0.f;
  const int NP = (M + 1) >> 1;
  for (int mp = blockIdx.x; mp < NP; mp += gridDim.x) {
    const int mA = mp * 2, mB = mA + 1;
    const bool hasB = (mB < M);
    const int mBs = hasB ? mB : mA;
    int rA[5], cA[5], rB[5], cBx[5];
    const int2* xpA = (const int2*)(x + mA * 10);
    const int2* xpB = (const int2*)(x + mBs * 10);
#pragma unroll
    for (int cc = 0; cc < 5; ++cc) {
      int2 tA = xpA[cc]; rA[cc] = tA.x; cA[cc] = tA.y;
      int2 tB = xpB[cc]; rB[cc] = tB.x; cBx[cc] = tB.y;
    }
    float a0A[4], a0B[4];
#pragma unroll
    for (int xx = 0; xx < 4; ++xx) {
      float vA = cb, vB = cb;
#pragma unroll
      for (int cc = 0; cc < 5; ++cc) {
        vA += Wk[conv_idx(rA[cc] - y, cA[cc] - xx, cc)];
        vB += Wk[conv_idx(rB[cc] - y, cBx[cc] - xx, cc)];
      }
      a0A[xx] = fmaxf(al * vA + be, 0.f);
      a0B[xx] = fmaxf(al * vB + be, 0.f);
    }
    vf2 aAp[2], aBp[2];
    aAp[0].x = a0A[0]; aAp[0].y = a0A[1];
    aAp[1].x = a0A[2]; aAp[1].y = a0A[3];
    aBp[0].x = a0B[0]; aBp[0].y = a0B[1];
    aBp[1].x = a0B[2]; aBp[1].y = a0B[3];
    __builtin_amdgcn_sched_barrier(0);
    vf2 r1A[16], r1B[16];
#pragma unroll
    for (int o2 = 0; o2 < 16; ++o2) {
      const int oa = 2 * o2, ob = oa + 1;
      vf2 w0 = wrp[oa * 5], w1 = wrp[oa * 5 + 1];
      vf2 w2 = wrp[ob * 5], w3 = wrp[ob * 5 + 1];
      const float basea = b_rank[oa] + zbg * cu[oa];
      const float baseb = b_rank[ob] + zbg * cu[ob];
      vf2 accAa = aAp[0] * w0; accAa += aAp[1] * w1;
      vf2 accAb = aAp[0] * w2; accAb += aAp[1] * w3;
      vf2 accBa = aBp[0] * w0; accBa += aBp[1] * w1;
      vf2 accBb = aBp[0] * w2; accBb += aBp[1] * w3;
      vf2 ra, rb;
      ra.x = fmaxf(basea + accAa.x + accAa.y, 0.f);
      ra.y = fmaxf(baseb + accAb.x + accAb.y, 0.f);
      rb.x = fmaxf(basea + accBa.x + accBa.y, 0.f);
      rb.y = fmaxf(baseb + accBb.x + accBb.y, 0.f);
      r1A[o2] = ra;
      r1B[o2] = rb;
    }
    __builtin_amdgcn_sched_barrier(0);
    float sBm = 0.f, ssBm = 0.f;
#pragma unroll
    for (int chv = 0; chv < 8; ++chv) {
      float accA[4], accB[4];
#pragma unroll
      for (int u = 0; u < 4; ++u) {
        const int o = chv * 4 + u;
        vf2 a2A = {0.f, 0.f}, a2B = {0.f, 0.f};
#pragma unroll
        for (int i = 0; i < 16; ++i) {
          vf2 w = w1p[o * 16 + i];
          a2A += r1A[i] * w;
          a2B += r1B[i] * w;
        }
        const float bb = b_h1[o];
        float aA = bb + a2A.x + a2A.y;
        float aB = bb + a2B.x + a2B.y;
        accA[u] = aA; accB[u] = aB;
        sAcc += aA; ssAcc += aA * aA;
        sBm += aB;  ssBm += aB * aB;
      }
      float4 stA; stA.x = accA[0]; stA.y = accA[1]; stA.z = accA[2]; stA.w = accA[3];
      t1v[((size_t)mA * 8 + chv) * 256 + tid] = stA;
      if (hasB) {
        float4 stB; stB.x = accB[0]; stB.y = accB[1]; stB.z = accB[2]; stB.w = accB[3];
        t1v[((size_t)mB * 8 + chv) * 256 + tid] = stB;
      }
      __builtin_amdgcn_sched_barrier(0);
    }
    if (hasB) { sAcc += sBm; ssAcc += ssBm; }
  }
  sAcc  += __shfl_xor(sAcc, 1);  sAcc  += __shfl_xor(sAcc, 2);
  ssAcc += __shfl_xor(ssAcc, 1); ssAcc += __shfl_xor(ssAcc, 2);
  if (y == 0) {
    atomicAdd(&ws[WS_SUM1 + k], sAcc);
    atomicAdd(&ws[WS_SSQ1 + k], ssAcc);
  }
}

// ---------------------------------------------------------------------------
// Kernel 4: finalize BN1; background a1_bg -> t2_bg; seed BN2 stats.
__global__ __launch_bounds__(64) void k_fin1(
    const float* __restrict__ g1, const float* __restrict__ b1,
    const float* __restrict__ w_h2, const float* __restrict__ b_h2,
    float* __restrict__ ws, int M) {
  const int k = threadIdx.x;
  const float n1 = (float)M * 11.f * 32.f;
  const float S = ws[WS_SUM1 + k], SS = ws[WS_SSQ1 + k];
  const float mu = S / n1;
  const float var = SS / n1 - mu * mu;
  const float rstd = rsqrtf(var + EPSV);
  const float al = rstd * g1[k];
  const float be = b1[k] - mu * al;
  ws[WS_AL1 + k] = al;
  ws[WS_BE1 + k] = be;
  float a1bg[32];
#pragma unroll
  for (int o = 0; o < 32; ++o)
    a1bg[o] = fmaxf(al * ws[WS_T1BG + k * 32 + o] + be, 0.f);
  float sb = 0.f, ssb = 0.f;
  for (int p = 0; p < 16; ++p) {
    float acc = b_h2[p];
#pragma unroll
    for (int o = 0; o < 32; ++o) acc += a1bg[o] * w_h2[p * 32 + o];
    ws[WS_T2BG + k * 16 + p] = acc;
    sb += acc;
    ssb += acc * acc;
  }
  ws[WS_SUM2 + k] = 7.f * (float)M * sb;
  ws[WS_SSQ2 + k] = 7.f * (float)M * ssb;
}

// ---------------------------------------------------------------------------
// Kernel 5 (fast path): DUAL-m t1 -> BN1+relu -> layer2 -> t2 (in place).
__global__ __launch_bounds__(256) void k_t2(
    const float* __restrict__ w_h2, const float* __restrict__ b_h2,
    float* __restrict__ ws, float* __restrict__ t1, int M) {
  const int tid = threadIdx.x;
  const int y = tid & 3, k = tid >> 2;
  const float al1 = ws[WS_AL1 + k], be1 = ws[WS_BE1 + k];
  const vf2* w2p = (const vf2*)w_h2;
  float4* t1v = (float4*)t1;
  float sAcc = 0.f, ssAcc = 0.f;
  const int NP = (M + 1) >> 1;
  for (int mp = blockIdx.x; mp < NP; mp += gridDim.x) {
    const int mA = mp * 2, mB = mA + 1;
    const bool hasB = (mB < M);
    const int mBs = hasB ? mB : mA;
    vf2 a1A[16], a1B[16];
#pragma unroll
    for (int chv = 0; chv < 8; ++chv) {
      float4 vA = t1v[((size_t)mA * 8 + chv) * 256 + tid];
      float4 vB = t1v[((size_t)mBs * 8 + chv) * 256 + tid];
      vf2 pA0, pA1, pB0, pB1;
      pA0.x = fmaxf(al1 * vA.x + be1, 0.f);
      pA0.y = fmaxf(al1 * vA.y + be1, 0.f);
      pA1.x = fmaxf(al1 * vA.z + be1, 0.f);
      pA1.y = fmaxf(al1 * vA.w + be1, 0.f);
      pB0.x = fmaxf(al1 * vB.x + be1, 0.f);
      pB0.y = fmaxf(al1 * vB.y + be1, 0.f);
      pB1.x = fmaxf(al1 * vB.z + be1, 0.f);
      pB1.y = fmaxf(al1 * vB.w + be1, 0.f);
      a1A[chv * 2] = pA0; a1A[chv * 2 + 1] = pA1;
      a1B[chv * 2] = pB0; a1B[chv * 2 + 1] = pB1;
    }
    __builtin_amdgcn_sched_barrier(0);
    float sBm = 0.f, ssBm = 0.f;
#pragma unroll
    for (int pv = 0; pv < 4; ++pv) {
      float accA[4], accB[4];
#pragma unroll
      for (int u = 0; u < 4; ++u) {
        const int p = pv * 4 + u;
        vf2 a2A = {0.f, 0.f}, a2B = {0.f, 0.f};
#pragma unroll
        for (int i = 0; i < 16; ++i) {
          vf2 w = w2p[p * 16 + i];
          a2A += a1A[i] * w;
          a2B += a1B[i] * w;
        }
        const float bb = b_h2[p];
        float aA = bb + a2A.x + a2A.y;
        float aB = bb + a2B.x + a2B.y;
        accA[u] = aA; accB[u] = aB;
        sAcc += aA; ssAcc += aA * aA;
        sBm += aB;  ssBm += aB * aB;
      }
      float4 stA; stA.x = accA[0]; stA.y = accA[1]; stA.z = accA[2]; stA.w = accA[3];
      t1v[((size_t)mA * 8 + pv) * 256 + tid] = stA;
      if (hasB) {
        float4 stB; stB.x = accB[0]; stB.y = accB[1]; stB.z = accB[2]; stB.w = accB[3];
        t1v[((size_t)mB * 8 + pv) * 256 + tid] = stB;
      }
      __builtin_amdgcn_sched_barrier(0);
    }
    if (hasB) { sAcc += sBm; ssAcc += ssBm; }
  }
  sAcc  += __shfl_xor(sAcc, 1);  sAcc  += __shfl_xor(sAcc, 2);
  ssAcc += __shfl_xor(ssAcc, 1); ssAcc += __shfl_xor(ssAcc, 2);
  if (y == 0) {
    atomicAdd(&ws[WS_SUM2 + k], sAcc);
    atomicAdd(&ws[WS_SSQ2 + k], ssAcc);
  }
}

// ---------------------------------------------------------------------------
// Kernel 6: finalize BN2; background a2_bg; background output constant.
__global__ __launch_bounds__(64) void k_fin2(
    const float* __restrict__ g2, const float* __restrict__ b2,
    const float* __restrict__ w_out, const float* __restrict__ b_out,
    float* __restrict__ ws, int M) {
  __shared__ float red[64 * 9];
  const int k = threadIdx.x;
  const float n2 = (float)M * 11.f * 16.f;
  const float S = ws[WS_SUM2 + k], SS = ws[WS_SSQ2 + k];
  const float mu = S / n2;
  const float var = SS / n2 - mu * mu;
  const float rstd = rsqrtf(var + EPSV);
  const float al = rstd * g2[k];
  const float be = b2[k] - mu * al;
  ws[WS_AL2 + k] = al;
  ws[WS_BE2 + k] = be;
  float a2bg[16];
#pragma unroll
  for (int p = 0; p < 16; ++p) {
    a2bg[p] = fmaxf(al * ws[WS_T2BG + k * 16 + p] + be, 0.f);
    ws[WS_A2BG + k * 16 + p] = a2bg[p];
  }
  for (int j = 0; j < 9; ++j) {
    float acc = 0.f;
#pragma unroll
    for (int p = 0; p < 16; ++p) {
      float wsum = 0.f;
#pragma unroll
      for (int yy = 4; yy < 11; ++yy)
        wsum += w_out[j * 11264 + k * 176 + yy * 16 + p];
      acc += a2bg[p] * wsum;
    }
    red[k * 9 + j] = acc;
  }
  __syncthreads();
  if (k < 9) {
    float acc = b_out[k];
    for (int t = 0; t < 64; ++t) acc += red[t * 9 + k];
    ws[WS_OC + k] = acc;
  }
}

// ---------------------------------------------------------------------------
// Kernel 7 (fast path): DUAL-m t2 -> BN2+relu -> output dot + reduce.
__global__ __launch_bounds__(256) void k_out(
    const float* __restrict__ w_out, const float* __restrict__ ws,
    const float* __restrict__ t1, float* __restrict__ out, int M) {
  __shared__ float sOC[9];
  __shared__ float sRedA[4][9], sRedB[4][9];
  if (threadIdx.x < 9) sOC[threadIdx.x] = ws[WS_OC + threadIdx.x];
  __syncthreads();
  const int tid = threadIdx.x;
  const int lane = tid & 63, wv = tid >> 6;
  const int y = tid & 3, k = tid >> 2;
  const float al2 = ws[WS_AL2 + k], be2 = ws[WS_BE2 + k];
  const float4* wo = (const float4*)(w_out + k * 176 + y * 16);
  const float4* t1v = (const float4*)t1;
  const int NP = (M + 1) >> 1;
  bool first = true;
  for (int mp = blockIdx.x; mp < NP; mp += gridDim.x) {
    if (!first) __syncthreads();
    first = false;
    const int mA = mp * 2, mB = mA + 1;
    const bool hasB = (mB < M);
    const int mBs = hasB ? mB : mA;
    vf2 a2A[8], a2B[8];
#pragma unroll
    for (int iv = 0; iv < 4; ++iv) {
      float4 vA = t1v[((size_t)mA * 8 + iv) * 256 + tid];
      float4 vB = t1v[((size_t)mBs * 8 + iv) * 256 + tid];
      vf2 pA0, pA1, pB0, pB1;
      pA0.x = fmaxf(al2 * vA.x + be2, 0.f);
      pA0.y = fmaxf(al2 * vA.y + be2, 0.f);
      pA1.x = fmaxf(al2 * vA.z + be2, 0.f);
      pA1.y = fmaxf(al2 * vA.w + be2, 0.f);
      pB0.x = fmaxf(al2 * vB.x + be2, 0.f);
      pB0.y = fmaxf(al2 * vB.y + be2, 0.f);
      pB1.x = fmaxf(al2 * vB.z + be2, 0.f);
      pB1.y = fmaxf(al2 * vB.w + be2, 0.f);
      a2A[iv * 2] = pA0; a2A[iv * 2 + 1] = pA1;
      a2B[iv * 2] = pB0; a2B[iv * 2 + 1] = pB1;
    }
    float poA[9], poB[9];
#pragma unroll
    for (int j = 0; j < 9; ++j) {
      float4 w0 = wo[j * 2816 + 0], w1 = wo[j * 2816 + 1];
      float4 w2 = wo[j * 2816 + 2], w3 = wo[j * 2816 + 3];
      vf2 aA = {0.f, 0.f}, aB = {0.f, 0.f};
      vf2 t;
      t.x = w0.x; t.y = w0.y; aA += a2A[0] * t; aB += a2B[0] * t;
      t.x = w0.z; t.y = w0.w; aA += a2A[1] * t; aB += a2B[1] * t;
      t.x = w1.x; t.y = w1.y; aA += a2A[2] * t; aB += a2B[2] * t;
      t.x = w1.z; t.y = w1.w; aA += a2A[3] * t; aB += a2B[3] * t;
      t.x = w2.x; t.y = w2.y; aA += a2A[4] * t; aB += a2B[4] * t;
      t.x = w2.z; t.y = w2.w; aA += a2A[5] * t; aB += a2B[5] * t;
      t.x = w3.x; t.y = w3.y; aA += a2A[6] * t; aB += a2B[6] * t;
      t.x = w3.z; t.y = w3.w; aA += a2A[7] * t; aB += a2B[7] * t;
      poA[j] = aA.x + aA.y;
      poB[j] = aB.x + aB.y;
    }
#pragma unroll
    for (int j = 0; j < 9; ++j) {
      float vA = poA[j], vB = poB[j];
      vA += __shfl_xor(vA, 1);  vB += __shfl_xor(vB, 1);
      vA += __shfl_xor(vA, 2);  vB += __shfl_xor(vB, 2);
      vA += __shfl_xor(vA, 4);  vB += __shfl_xor(vB, 4);
      vA += __shfl_xor(vA, 8);  vB += __shfl_xor(vB, 8);
      vA += __shfl_xor(vA, 16); vB += __shfl_xor(vB, 16);
      vA += __shfl_xor(vA, 32); vB += __shfl_xor(vB, 32);
      poA[j] = vA; poB[j] = vB;
    }
    if (lane == 0) {
#pragma unroll
      for (int j = 0; j < 9; ++j) { sRedA[wv][j] = poA[j]; sRedB[wv][j] = poB[j]; }
    }
    __syncthreads();
    if (tid < 9) {
      float acc = sOC[tid];
#pragma unroll
      for (int w2i = 0; w2i < 4; ++w2i) acc += sRedA[w2i][tid];
      out[mA * 9 + tid] = acc;
    } else if (tid >= 64 && tid < 73 && hasB) {
      const int j = tid - 64;
      float acc = sOC[j];
#pragma unroll
      for (int w2i = 0; w2i < 4; ++w2i) acc += sRedB[w2i][j];
      out[mB * 9 + j] = acc;
    }
  }
}

// ===========================================================================
// FALLBACK PATH (ws too small): self-contained recompute kernels.
// ===========================================================================
__global__ __launch_bounds__(256) void k_stats0(
    const int* __restrict__ x, const float* __restrict__ conv_w,
    const float* __restrict__ conv_b, float* __restrict__ ws, int M) {
  __shared__ float sW[CONV_LDS];
  stage_conv(sW, conv_w, 256);
  __syncthreads();
  const int tid = threadIdx.x;
  const int mg = tid & 3;
  const int k  = tid >> 2;
  const float cb = conv_b[k];
  const float* Wk = &sW[k * 81];
  float s = 0.f, ss = 0.f;
  for (int m = blockIdx.x * 4 + mg; m < M; m += gridDim.x * 4) {
    int r[5], c[5];
    const int2* xp = (const int2*)(x + m * 10);
#pragma unroll
    for (int cc = 0; cc < 5; ++cc) { int2 t = xp[cc]; r[cc] = t.x; c[cc] = t.y; }
#pragma unroll
    for (int y = 0; y < 4; ++y) {
#pragma unroll
      for (int xx = 0; xx < 4; ++xx) {
        float v = cb;
#pragma unroll
        for (int cc = 0; cc < 5; ++cc)
          v += Wk[conv_idx(r[cc] - y, c[cc] - xx, cc)];
        s += v;
        ss += v * v;
      }
      __builtin_amdgcn_sched_barrier(0);
    }
  }
  s  += __shfl_xor(s, 1);  s  += __shfl_xor(s, 2);
  ss += __shfl_xor(ss, 1); ss += __shfl_xor(ss, 2);
  if (mg == 0) {
    atomicAdd(&ws[WS_SUM0 + k], s);
    atomicAdd(&ws[WS_SSQ0 + k], ss);
  }
}

__global__ __launch_bounds__(256) void k_stats1(
    const int* __restrict__ x, const float* __restrict__ conv_w,
    const float* __restrict__ conv_b, const float* __restrict__ w_rank,
    const float* __restrict__ b_rank, const float* __restrict__ w_h1,
    const float* __restrict__ b_h1, float* __restrict__ ws, int M) {
  __shared__ float sW[CONV_LDS];
  stage_conv(sW, conv_w, 256);
  __syncthreads();
  const int tid = threadIdx.x;
  const int y = tid & 3, k = tid >> 2;
  const float cb = conv_b[k];
  const float al = ws[WS_AL0 + k], be = ws[WS_BE0 + k], zbg = ws[WS_ZBG + k];
  const float* Wk = &sW[k * 81];
  const float* cu = ws + WS_CU;
  float sAcc = 0.f, ssAcc = 0.f;
  for (int m = blockIdx.x; m < M; m += gridDim.x) {
    int r[5], c[5];
    const int2* xp = (const int2*)(x + m * 10);
#pragma unroll
    for (int cc = 0; cc < 5; ++cc) { int2 t = xp[cc]; r[cc] = t.x; c[cc] = t.y; }
    float a0[4];
#pragma unroll
    for (int xx = 0; xx < 4; ++xx) {
      float v = cb;
#pragma unroll
      for (int cc = 0; cc < 5; ++cc)
        v += Wk[conv_idx(r[cc] - y, c[cc] - xx, cc)];
      a0[xx] = fmaxf(al * v + be, 0.f);
    }
    __builtin_amdgcn_sched_barrier(0);
    float r1[32];
#pragma unroll
    for (int o = 0; o < 32; ++o) {
      float acc = b_rank[o] + zbg * cu[o];
#pragma unroll
      for (int xx = 0; xx < 4; ++xx) acc += a0[xx] * w_rank[o * 10 + xx];
      r1[o] = fmaxf(acc, 0.f);
    }
    __builtin_amdgcn_sched_barrier(0);
    float s1 = 0.f, ss1 = 0.f;
#pragma unroll
    for (int ch = 0; ch < 4; ++ch) {
#pragma unroll
      for (int u = 0; u < 8; ++u) {
        const int o = ch * 8 + u;
        float acc = b_h1[o];
#pragma unroll
        for (int i = 0; i < 32; ++i) acc += r1[i] * w_h1[o * 32 + i];
        s1 += acc;
        ss1 += acc * acc;
      }
      __builtin_amdgcn_sched_barrier(0);
    }
    sAcc += s1;
    ssAcc += ss1;
  }
  sAcc  += __shfl_xor(sAcc, 1);  sAcc  += __shfl_xor(sAcc, 2);
  ssAcc += __shfl_xor(ssAcc, 1); ssAcc += __shfl_xor(ssAcc, 2);
  if (y == 0) {
    atomicAdd(&ws[WS_SUM1 + k], sAcc);
    atomicAdd(&ws[WS_SSQ1 + k], ssAcc);
  }
}

__global__ __launch_bounds__(256) void k_stats2(
    const int* __restrict__ x, const float* __restrict__ conv_w,
    const float* __restrict__ conv_b, const float* __restrict__ w_rank,
    const float* __restrict__ b_rank, const float* __restrict__ w_h1,
    const float* __restrict__ b_h1, const float* __restrict__ w_h2,
    const float* __restrict__ b_h2, float* __restrict__ ws, int M) {
  __shared__ float sW[CONV_LDS];
  stage_conv(sW, conv_w, 256);
  __syncthreads();
  const int tid = threadIdx.x;
  const int y = tid & 3, k = tid >> 2;
  const float cb = conv_b[k];
  const float al = ws[WS_AL0 + k], be = ws[WS_BE0 + k], zbg = ws[WS_ZBG + k];
  const float al1 = ws[WS_AL1 + k], be1 = ws[WS_BE1 + k];
  const float* Wk = &sW[k * 81];
  const float* cu = ws + WS_CU;
  float sAcc = 0.f, ssAcc = 0.f;
  for (int m = blockIdx.x; m < M; m += gridDim.x) {
    int r[5], c[5];
    const int2* xp = (const int2*)(x + m * 10);
#pragma unroll
    for (int cc = 0; cc < 5; ++cc) { int2 t = xp[cc]; r[cc] = t.x; c[cc] = t.y; }
    float a0[4];
#pragma unroll
    for (int xx = 0; xx < 4; ++xx) {
      float v = cb;
#pragma unroll
      for (int cc = 0; cc < 5; ++cc)
        v += Wk[conv_idx(r[cc] - y, c[cc] - xx, cc)];
      a0[xx] = fmaxf(al * v + be, 0.f);
    }
    __builtin_amdgcn_sched_barrier(0);
    float r1[32];
#pragma unroll
    for (int o = 0; o < 32; ++o) {
      float acc = b_rank[o] + zbg * cu[o];
#pragma unroll
      for (int xx = 0; xx < 4; ++xx) acc += a0[xx] * w_rank[o * 10 + xx];
      r1[o] = fmaxf(acc, 0.f);
    }
    __builtin_amdgcn_sched_barrier(0);
    float t2[16];
#pragma unroll
    for (int p = 0; p < 16; ++p) t2[p] = b_h2[p];
#pragma unroll
    for (int ch = 0; ch < 4; ++ch) {
      float a1c[8];
#pragma unroll
      for (int u = 0; u < 8; ++u) {
        const int o = ch * 8 + u;
        float acc = b_h1[o];
#pragma unroll
        for (int i = 0; i < 32; ++i) acc += r1[i] * w_h1[o * 32 + i];
        a1c[u] = fmaxf(al1 * acc + be1, 0.f);
      }
      __builtin_amdgcn_sched_barrier(0);
#pragma unroll
      for (int p = 0; p < 16; ++p) {
        float acc = t2[p];
#pragma unroll
        for (int u = 0; u < 8; ++u) acc += a1c[u] * w_h2[p * 32 + ch * 8 + u];
        t2[p] = acc;
      }
      __builtin_amdgcn_sched_barrier(0);
    }
    float s2l = 0.f, ss2l = 0.f;
#pragma unroll
    for (int p = 0; p < 16; ++p) { s2l += t2[p]; ss2l += t2[p] * t2[p]; }
    sAcc += s2l;
    ssAcc += ss2l;
  }
  sAcc  += __shfl_xor(sAcc, 1);  sAcc  += __shfl_xor(sAcc, 2);
  ssAcc += __shfl_xor(ssAcc, 1); ssAcc += __shfl_xor(ssAcc, 2);
  if (y == 0) {
    atomicAdd(&ws[WS_SUM2 + k], sAcc);
    atomicAdd(&ws[WS_SSQ2 + k], ssAcc);
  }
}

__global__ __launch_bounds__(256) void k_final(
    const int* __restrict__ x, const float* __restrict__ conv_w,
    const float* __restrict__ conv_b, const float* __restrict__ w_rank,
    const float* __restrict__ b_rank, const float* __restrict__ w_h1,
    const float* __restrict__ b_h1, const float* __restrict__ w_h2,
    const float* __restrict__ b_h2, const float* __restrict__ w_out,
    const float* __restrict__ ws, float* __restrict__ out, int M) {
  __shared__ float sW[CONV_LDS];
  __shared__ float sOC[9];
  __shared__ float sRed[4][9];
  stage_conv(sW, conv_w, 256);
  if (threadIdx.x < 9) sOC[threadIdx.x] = ws[WS_OC + threadIdx.x];
  __syncthreads();
  const int tid = threadIdx.x;
  const int lane = tid & 63, wv = tid >> 6;
  const int y = tid & 3, k = tid >> 2;
  const float cb = conv_b[k];
  const float al = ws[WS_AL0 + k], be = ws[WS_BE0 + k], zbg = ws[WS_ZBG + k];
  const float al1 = ws[WS_AL1 + k], be1 = ws[WS_BE1 + k];
  const float al2 = ws[WS_AL2 + k], be2 = ws[WS_BE2 + k];
  const float* Wk = &sW[k * 81];
  const float* cu = ws + WS_CU;
  const float4* wo = (const float4*)(w_out + k * 176 + y * 16);
  bool first = true;
  for (int m = blockIdx.x; m < M; m += gridDim.x) {
    if (!first) __syncthreads();
    first = false;
    int r[5], c[5];
    const int2* xp = (const int2*)(x + m * 10);
#pragma unroll
    for (int cc = 0; cc < 5; ++cc) { int2 t = xp[cc]; r[cc] = t.x; c[cc] = t.y; }
    float a0[4];
#pragma unroll
    for (int xx = 0; xx < 4; ++xx) {
      float v = cb;
#pragma unroll
      for (int cc = 0; cc < 5; ++cc)
        v += Wk[conv_idx(r[cc] - y, c[cc] - xx, cc)];
      a0[xx] = fmaxf(al * v + be, 0.f);
    }
    __builtin_amdgcn_sched_barrier(0);
    float r1[32];
#pragma unroll
    for (int o = 0; o < 32; ++o) {
      float acc = b_rank[o] + zbg * cu[o];
#pragma unroll
      for (int xx = 0; xx < 4; ++xx) acc += a0[xx] * w_rank[o * 10 + xx];
      r1[o] = fmaxf(acc, 0.f);
    }
    __builtin_amdgcn_sched_barrier(0);
    float t2[16];
#pragma unroll
    for (int p = 0; p < 16; ++p) t2[p] = b_h2[p];
#pragma unroll
    for (int ch = 0; ch < 4; ++ch) {
      float a1c[8];
#pragma unroll
      for (int u = 0; u < 8; ++u) {
        const int o = ch * 8 + u;
        float acc = b_h1[o];
#pragma unroll
        for (int i = 0; i < 32; ++i) acc += r1[i] * w_h1[o * 32 + i];
        a1c[u] = fmaxf(al1 * acc + be1, 0.f);
      }
      __builtin_amdgcn_sched_barrier(0);
#pragma unroll
      for (int p = 0; p < 16; ++p) {
        float acc = t2[p];
#pragma unroll
        for (int u = 0; u < 8; ++u) acc += a1c[u] * w_h2[p * 32 + ch * 8 + u];
        t2[p] = acc;
      }
      __builtin_amdgcn_sched_barrier(0);
    }
    float a2[16];
#pragma unroll
    for (int p = 0; p < 16; ++p) a2[p] = fmaxf(al2 * t2[p] + be2, 0.f);
    float po[9];
#pragma unroll
    for (int j = 0; j < 9; ++j) {
      float4 w0 = wo[j * 2816 + 0], w1 = wo[j * 2816 + 1];
      float4 w2 = wo[j * 2816 + 2], w3 = wo[j * 2816 + 3];
      po[j] = a2[0] * w0.x + a2[1] * w0.y + a2[2] * w0.z + a2[3] * w0.w
            + a2[4] * w1.x + a2[5] * w1.y + a2[6] * w1.z + a2[7] * w1.w
            + a2[8] * w2.x + a2[9] * w2.y + a2[10] * w2.z + a2[11] * w2.w
            + a2[12] * w3.x + a2[13] * w3.y + a2[14] * w3.z + a2[15] * w3.w;
    }
#pragma unroll
    for (int j = 0; j < 9; ++j) {
      float v = po[j];
      v += __shfl_xor(v, 1);
      v += __shfl_xor(v, 2);
      v += __shfl_xor(v, 4);
      v += __shfl_xor(v, 8);
      v += __shfl_xor(v, 16);
      v += __shfl_xor(v, 32);
      po[j] = v;
    }
    if (lane == 0) {
#pragma unroll
      for (int j = 0; j < 9; ++j) sRed[wv][j] = po[j];
    }
    __syncthreads();
    if (tid < 9) {
      float acc = sOC[tid];
#pragma unroll
      for (int w2i = 0; w2i < 4; ++w2i) acc += sRed[w2i][tid];
      out[m * 9 + tid] = acc;
    }
  }
}

// ---------------------------------------------------------------------------
extern "C" void kernel_launch(void* const* d_in, const int* in_sizes, int n_in,
                              void* d_out, int out_size, void* d_ws, size_t ws_size,
                              hipStream_t stream) {
  const int*   x      = (const int*)d_in[0];
  const float* conv_w = (const float*)d_in[1];
  const float* conv_b = (const float*)d_in[2];
  const float* bn0_g  = (const float*)d_in[3];
  const float* bn0_b  = (const float*)d_in[4];
  const float* w_rank = (const float*)d_in[5];
  const float* b_rank = (const float*)d_in[6];
  const float* w_h1   = (const float*)d_in[7];
  const float* b_h1   = (const float*)d_in[8];
  const float* bn1_g  = (const float*)d_in[9];
  const float* bn1_b  = (const float*)d_in[10];
  const float* w_h2   = (const float*)d_in[11];
  const float* b_h2   = (const float*)d_in[12];
  const float* bn2_g  = (const float*)d_in[13];
  const float* bn2_b  = (const float*)d_in[14];
  const float* w_out  = (const float*)d_in[15];
  const float* b_out  = (const float*)d_in[16];
  float* out = (float*)d_out;
  float* ws  = (float*)d_ws;
  const int M = in_sizes[0] / 10;
  const size_t need = ((size_t)WS_T1 + (size_t)M * 8192) * sizeof(float);
  const int NP = (M + 1) >> 1;
  const int gridp = NP < 2048 ? NP : 2048;

  hipMemsetAsync(ws, 0, 384 * sizeof(float), stream);

  if (ws_size >= need) {
    float* t1 = ws + WS_T1;
    k_prep<<<8, 256, 0, stream>>>(conv_w, ws);
    k_stats0f<<<1024, 256, 0, stream>>>(x, conv_b, ws, M);
    k_fin0<<<1, 64, 0, stream>>>(conv_b, bn0_g, bn0_b, w_rank, b_rank, w_h1, b_h1, ws, M);
    k_t1<<<gridp, 256, 0, stream>>>(x, conv_b, w_rank, b_rank, w_h1, b_h1, ws, t1, M);
    k_fin1<<<1, 64, 0, stream>>>(bn1_g, bn1_b, w_h2, b_h2, ws, M);
    k_t2<<<gridp, 256, 0, stream>>>(w_h2, b_h2, ws, t1, M);
    k_fin2<<<1, 64, 0, stream>>>(bn2_g, bn2_b, w_out, b_out, ws, M);
    k_out<<<gridp, 256, 0, stream>>>(w_out, ws, t1, out, M);
  } else {
    k_stats0<<<512, 256, 0, stream>>>(x, conv_w, conv_b, ws, M);
    k_fin0<<<1, 64, 0, stream>>>(conv_b, bn0_g, bn0_b, w_rank, b_rank, w_h1, b_h1, ws, M);
    k_stats1<<<1024, 256, 0, stream>>>(x, conv_w, conv_b, w_rank, b_rank, w_h1, b_h1,
                                       ws, M);
    k_fin1<<<1, 64, 0, stream>>>(bn1_g, bn1_b, w_h2, b_h2, ws, M);
    k_stats2<<<1024, 256, 0, stream>>>(x, conv_w, conv_b, w_rank, b_rank, w_h1, b_h1,
                                       w_h2, b_h2, ws, M);
    k_fin2<<<1, 64, 0, stream>>>(bn2_g, bn2_b, w_out, b_out, ws, M);
    k_final<<<1024, 256, 0, stream>>>(x, conv_w, conv_b, w_rank, b_rank, w_h1, b_h1,
                                      w_h2, b_h2, w_out, ws, out, M);
  }
}